// Round 2
// baseline (292.032 us; speedup 1.0000x reference)
//
#include <hip/hip_runtime.h>
#include <hip/hip_bf16.h>
#include <math.h>

using bf16 = __hip_bfloat16;
using bf162 = __hip_bfloat162;

typedef __bf16 bf16x8 __attribute__((ext_vector_type(8)));
typedef float floatx4 __attribute__((ext_vector_type(4)));

constexpr int NB = 4, HH = 96, WW = 96, CC = 128, GG = 8, PP = 9;
constexpr int HW = HH * WW;          // 9216
constexpr int NPIX = NB * HW;        // 36864

__device__ __forceinline__ float ld1(const float* p) { return *p; }
__device__ __forceinline__ float ld1(const bf16* p)  { return __bfloat162float(*p); }
__device__ __forceinline__ void st1(float* p, float v) { *p = v; }
__device__ __forceinline__ void st1(bf16* p, float v)  { *p = __float2bfloat16(v); }
__device__ __forceinline__ float b2f(bf16 v) { return __bfloat162float(v); }
__device__ __forceinline__ bf16 f2b(float v) { return __float2bfloat16(v); }
__device__ __forceinline__ float gelu_exact(float v) {
    return 0.5f * v * (1.0f + erff(v * 0.7071067811865475f));
}
__device__ __forceinline__ floatx4 MFMA(bf16x8 a, bf16x8 b, floatx4 c) {
    return __builtin_amdgcn_mfma_f32_16x16x32_bf16(a, b, c, 0, 0, 0);
}

// ---------------- one-time weight prep: f32 W[K][N] -> bf16 Wt[N][K] (+ bias concat)
struct PrepArgs {
    const float* src[6];
    bf16* dst[6];
    int K[6], N[6];
    int cum[7];
    const float* b_off; const float* b_msk; float* b_om;   // bias concat 216
};

__global__ __launch_bounds__(256) void prep_weights(PrepArgs pa, int total)
{
    int t = blockIdx.x * 256 + threadIdx.x;
    if (t >= total) return;
    if (t >= pa.cum[6]) {                 // bias concat tail
        int e = t - pa.cum[6];
        pa.b_om[e] = (e < 144) ? pa.b_off[e] : pa.b_msk[e - 144];
        return;
    }
    int i = 0;
    #pragma unroll
    for (int j = 0; j < 5; ++j) if (t >= pa.cum[j + 1]) i = j + 1;
    int e = t - pa.cum[i];
    int Ki = pa.K[i], Ni = pa.N[i];
    int n = e / Ki, k = e - n * Ki;
    pa.dst[i][e] = f2b(pa.src[i][(size_t)k * Ni + n]);
}

// ---------------- LayerNorm over C=128, one wave per pixel, 2 ch/lane
template<typename TI, typename TO>
__global__ __launch_bounds__(256) void ln_kernel(
    const TI* __restrict__ X, const float* __restrict__ g,
    const float* __restrict__ b, TO* __restrict__ out)
{
    int wave = (blockIdx.x * 256 + threadIdx.x) >> 6;
    int lane = threadIdx.x & 63;
    if (wave >= NPIX) return;
    const TI* xp = X + (size_t)wave * 128 + 2 * lane;
    float v0 = ld1(xp), v1 = ld1(xp + 1);
    float s = v0 + v1, q = v0 * v0 + v1 * v1;
    #pragma unroll
    for (int o = 32; o; o >>= 1) { s += __shfl_xor(s, o); q += __shfl_xor(q, o); }
    float mean = s * (1.0f / 128.0f);
    float rstd = rsqrtf(q * (1.0f / 128.0f) - mean * mean + 1e-5f);
    float g0 = g[2 * lane], g1 = g[2 * lane + 1];
    float b0 = b[2 * lane], b1 = b[2 * lane + 1];
    TO* op = out + (size_t)wave * 128 + 2 * lane;
    st1(op,     (v0 - mean) * rstd * g0 + b0);
    st1(op + 1, (v1 - mean) * rstd * g1 + b1);
}

// ---------------- depthwise 3x3 conv (SAME, zero pad) + LN + exact GELU. wave/pixel
__global__ __launch_bounds__(256) void dwconv_ln_gelu_kernel(
    const bf16* __restrict__ xln, const float* __restrict__ dwk,
    const float* __restrict__ dwb, const float* __restrict__ gam,
    const float* __restrict__ bet, bf16* __restrict__ out)
{
    int wave = (blockIdx.x * 256 + threadIdx.x) >> 6;
    int lane = threadIdx.x & 63;
    if (wave >= NPIX) return;
    int n = wave / HW; int rem = wave % HW;
    int y = rem / WW;  int x = rem % WW;
    const bf162* xp = (const bf162*)xln;
    float a0 = 0.f, a1 = 0.f;
    #pragma unroll
    for (int ky = 0; ky < 3; ++ky) {
        int yy = y + ky - 1;
        if (yy < 0 || yy >= HH) continue;
        #pragma unroll
        for (int kx = 0; kx < 3; ++kx) {
            int xx = x + kx - 1;
            if (xx < 0 || xx >= WW) continue;
            bf162 v = xp[((size_t)(n * HH + yy) * WW + xx) * 64 + lane];
            const float* w = dwk + (ky * 3 + kx) * CC + 2 * lane;
            a0 = fmaf(b2f(v.x), w[0], a0);
            a1 = fmaf(b2f(v.y), w[1], a1);
        }
    }
    a0 += dwb[2 * lane]; a1 += dwb[2 * lane + 1];
    float s = a0 + a1, q = a0 * a0 + a1 * a1;
    #pragma unroll
    for (int o = 32; o; o >>= 1) { s += __shfl_xor(s, o); q += __shfl_xor(q, o); }
    float mean = s * (1.0f / 128.0f);
    float rstd = rsqrtf(q * (1.0f / 128.0f) - mean * mean + 1e-5f);
    float h0 = gelu_exact((a0 - mean) * rstd * gam[2 * lane]     + bet[2 * lane]);
    float h1 = gelu_exact((a1 - mean) * rstd * gam[2 * lane + 1] + bet[2 * lane + 1]);
    bf162 o2; o2.x = f2b(h0); o2.y = f2b(h1);
    ((bf162*)out)[(size_t)wave * 64 + lane] = o2;
}

// ---------------- DCNv3 core: wave per pixel, fused mask-softmax + two-phase
__global__ __launch_bounds__(256) void dcn_core_kernel(
    const bf16* __restrict__ xproj, const bf16* __restrict__ omr,
    bf16* __restrict__ out)
{
    __shared__ int4   sOff[4][72];
    __shared__ float4 sW[4][72];
    __shared__ float  sRaw[4][72];
    int wv = threadIdx.x >> 6;
    int lane = threadIdx.x & 63;
    int pix = blockIdx.x * 4 + wv;
    int n = pix / HW; int rem = pix % HW;
    int iy = rem / WW; int ix = rem % WW;
    const bf16* om = omr + (size_t)pix * 216;

    for (int e = lane; e < 72; e += 64)
        sRaw[wv][e] = b2f(om[144 + e]);
    __syncthreads();

    for (int e = lane; e < 72; e += 64) {
        int g = e / 9, p = e - 9 * g;
        float mx = -1e30f;
        #pragma unroll
        for (int i = 0; i < 9; ++i) mx = fmaxf(mx, sRaw[wv][g * 9 + i]);
        float ssum = 0.f;
        #pragma unroll
        for (int i = 0; i < 9; ++i) ssum += __expf(sRaw[wv][g * 9 + i] - mx);
        float mw = __expf(sRaw[wv][e] - mx) / ssum;

        float ox = b2f(om[g * 18 + 2 * p]);
        float oy = b2f(om[g * 18 + 2 * p + 1]);
        int kx = p / 3 - 1, ky = p % 3 - 1;  // torch meshgrid 'ij': x slowest
        float px = (float)(ix + kx) + ox;
        float py = (float)(iy + ky) + oy;
        float fx0 = floorf(px), fy0 = floorf(py);
        int x0 = (int)fx0, y0 = (int)fy0;
        float fx = px - fx0, fy = py - fy0;
        bool vx0 = (x0 >= 0) & (x0 < WW), vx1 = (x0 + 1 >= 0) & (x0 + 1 < WW);
        bool vy0 = (y0 >= 0) & (y0 < HH), vy1 = (y0 + 1 >= 0) & (y0 + 1 < HH);
        float w00 = (1.f - fy) * (1.f - fx) * mw * (vy0 && vx0 ? 1.f : 0.f);
        float w01 = (1.f - fy) * fx         * mw * (vy0 && vx1 ? 1.f : 0.f);
        float w10 = fy * (1.f - fx)         * mw * (vy1 && vx0 ? 1.f : 0.f);
        float w11 = fy * fx                 * mw * (vy1 && vx1 ? 1.f : 0.f);
        int x0c = min(max(x0, 0), WW - 1), x1c = min(max(x0 + 1, 0), WW - 1);
        int y0c = min(max(y0, 0), HH - 1), y1c = min(max(y0 + 1, 0), HH - 1);
        sOff[wv][e] = make_int4((y0c * WW + x0c) * CC, (y0c * WW + x1c) * CC,
                                (y1c * WW + x0c) * CC, (y1c * WW + x1c) * CC);
        sW[wv][e] = make_float4(w00, w01, w10, w11);
    }
    __syncthreads();

    const bf16* xb = xproj + (size_t)n * HW * CC + 2 * lane;
    int gbase = (lane >> 3) * 9;
    float a0 = 0.f, a1 = 0.f;
    #pragma unroll
    for (int p = 0; p < 9; ++p) {
        int4 o = sOff[wv][gbase + p];
        float4 w = sW[wv][gbase + p];
        bf162 v00 = *(const bf162*)(xb + o.x);
        bf162 v01 = *(const bf162*)(xb + o.y);
        bf162 v10 = *(const bf162*)(xb + o.z);
        bf162 v11 = *(const bf162*)(xb + o.w);
        a0 += w.x * b2f(v00.x) + w.y * b2f(v01.x) + w.z * b2f(v10.x) + w.w * b2f(v11.x);
        a1 += w.x * b2f(v00.y) + w.y * b2f(v01.y) + w.z * b2f(v10.y) + w.w * b2f(v11.y);
    }
    bf162 o2; o2.x = f2b(a0); o2.y = f2b(a1);
    ((bf162*)out)[(size_t)pix * 64 + lane] = o2;
}

// ---------------- MFMA GEMM (R3-proven): Out[M,N] = A[M,K] @ Wt^T + bias
__global__ __launch_bounds__(256) void gemm_mfma_kernel(
    const bf16* __restrict__ A, const bf16* __restrict__ Wt,
    const float* __restrict__ bias, bf16* __restrict__ Out, int M, int Nn, int K)
{
    __shared__ __align__(16) __bf16 As[64][72];
    __shared__ __align__(16) __bf16 Bs[64][72];
    int tid = threadIdx.x;
    int wv = tid >> 6, lane = tid & 63;
    int bm = blockIdx.y * 64, bn = blockIdx.x * 64;
    int mI = lane & 15, q = lane >> 4;
    floatx4 acc[4] = {};

    for (int k0 = 0; k0 < K; k0 += 64) {
        #pragma unroll
        for (int cc = 0; cc < 2; ++cc) {
            int ch = tid * 2 + cc;               // 0..511
            int row = ch >> 3, ko = (ch & 7) * 8;
            *reinterpret_cast<uint4*>(&As[row][ko]) =
                *reinterpret_cast<const uint4*>(A + (size_t)(bm + row) * K + k0 + ko);
            int ng = bn + row;
            uint4 bv = make_uint4(0, 0, 0, 0);
            if (ng < Nn) bv = *reinterpret_cast<const uint4*>(Wt + (size_t)ng * K + k0 + ko);
            *reinterpret_cast<uint4*>(&Bs[row][ko]) = bv;
        }
        __syncthreads();
        #pragma unroll
        for (int kk = 0; kk < 64; kk += 32) {
            bf16x8 a = *reinterpret_cast<const bf16x8*>(&As[wv * 16 + mI][kk + q * 8]);
            #pragma unroll
            for (int t = 0; t < 4; ++t) {
                bf16x8 b = *reinterpret_cast<const bf16x8*>(&Bs[t * 16 + mI][kk + q * 8]);
                acc[t] = MFMA(a, b, acc[t]);
            }
        }
        __syncthreads();
    }
    int row0 = bm + wv * 16 + q * 4;
    #pragma unroll
    for (int t = 0; t < 4; ++t) {
        int col = bn + t * 16 + mI;
        if (col >= Nn) continue;
        float bs = bias[col];
        #pragma unroll
        for (int r = 0; r < 4; ++r)
            st1(Out + (size_t)(row0 + r) * Nn + col, acc[t][r] + bs);
    }
}

// ---------------- fused tail, v4: barrier-free MLP via wave-private row slices.
// R1 post-mortem: block critical path (~49us) was INVARIANT to tile size ->
// dominated by the 10-barrier lockstep phase chain, not throughput. v4 gives
// each wave 16 complete rows and the full 512 hidden contraction: GEMM1->gelu
// ->GEMM2 per 32-hid chunk is wave-private (h1 transposes through a private
// LDS strip, ordered by lgkmcnt only -- NO __syncthreads in the MLP). 16
// independent chunks/wave give the scheduler deep ILP; bw2 loads hide under
// gelu, next-chunk bw1 prefetched before the lgkm wait. Only 2 barriers remain
// (around LN2). Cost: each wave reads full w1T/w2T (L2-resident, ~3.7TB/s/XCD
// at predicted speed -- under the L2 roof).
__global__ __launch_bounds__(256, 3) void fused_tail_kernel(
    const bf16* __restrict__ ycore, const float* __restrict__ x,
    const bf16* __restrict__ w_outT, const float* __restrict__ b_out,
    const float* __restrict__ ln2g, const float* __restrict__ ln2b,
    const bf16* __restrict__ w1T, const float* __restrict__ b1,
    const bf16* __restrict__ w2T, const float* __restrict__ b2,
    float* __restrict__ out)
{
    __shared__ __align__(16) bf16 sStage[64 * 136];   // ycore tile, then h2 (LN2 out)
    __shared__ __align__(16) bf16 sXres[64 * 136];
    // per-wave ping-pong h1 strips: 16 rows x 32 cols, stride 40 (80B: 16B-aligned
    // ds_read_b128, start-bank 20r%32 -> 2-way alias only, free per m136)
    __shared__ __align__(16) bf16 sP[4][2][16 * 40];
    int tid = threadIdx.x, wv = tid >> 6, lane = tid & 63;
    int mI = lane & 15, q = lane >> 4;
    int bm = blockIdx.x * 64;

    // prefetch GEMM0 B-frags (8 independent 16B loads, in flight during staging)
    bf16x8 bw0[4][2];
    #pragma unroll
    for (int ks = 0; ks < 4; ++ks)
        #pragma unroll
        for (int ct = 0; ct < 2; ++ct)
            bw0[ks][ct] = *reinterpret_cast<const bf16x8*>(
                w_outT + (size_t)(wv * 32 + ct * 16 + mI) * 128 + ks * 32 + q * 8);

    // stage ycore tile (64 x 128) at stride 136
    #pragma unroll
    for (int i = 0; i < 4; ++i) {
        int s = tid + 256 * i;
        int row = s >> 4, ko = (s & 15) * 8;
        *reinterpret_cast<uint4*>(&sStage[row * 136 + ko]) =
            *reinterpret_cast<const uint4*>(ycore + (size_t)(bm + row) * 128 + ko);
    }
    __syncthreads();

    // GEMM0: wave covers out-proj cols wv*32..+31 over all 64 rows
    floatx4 acc0[4][2] = {};
    #pragma unroll
    for (int ks = 0; ks < 4; ++ks) {
        int k = ks * 32 + q * 8;
        bf16x8 a[4];
        #pragma unroll
        for (int rt = 0; rt < 4; ++rt)
            a[rt] = *reinterpret_cast<const bf16x8*>(&sStage[(rt * 16 + mI) * 136 + k]);
        #pragma unroll
        for (int ct = 0; ct < 2; ++ct)
            #pragma unroll
            for (int rt = 0; rt < 4; ++rt)
                acc0[rt][ct] = MFMA(a[rt], bw0[ks][ct], acc0[rt][ct]);
    }
    // xres tile -> sXres (bf16), with x residual (f32 global)
    #pragma unroll
    for (int rt = 0; rt < 4; ++rt)
        #pragma unroll
        for (int ct = 0; ct < 2; ++ct) {
            int col = wv * 32 + ct * 16 + mI;
            float bs = b_out[col];
            #pragma unroll
            for (int r = 0; r < 4; ++r) {
                int row = rt * 16 + q * 4 + r;
                float v = acc0[rt][ct][r] + bs + x[(size_t)(bm + row) * 128 + col];
                sXres[row * 136 + col] = f2b(v);
            }
        }
    __syncthreads();   // all GEMM0 reads of sStage done; sStage becomes h2

    // LN2: thread -> (row = tid>>2, 32 channels), quad shuffle reduce -> sStage
    {
        int row = tid >> 2, part = tid & 3;
        float s = 0.f, sq = 0.f;
        float vals[32];
        #pragma unroll
        for (int j = 0; j < 4; ++j) {
            bf16x8 v = *reinterpret_cast<const bf16x8*>(&sXres[row * 136 + part * 32 + j * 8]);
            #pragma unroll
            for (int e = 0; e < 8; ++e) {
                float f = (float)v[e];
                vals[j * 8 + e] = f; s += f; sq += f * f;
            }
        }
        s  += __shfl_xor(s, 1);  s += __shfl_xor(s, 2);
        sq += __shfl_xor(sq, 1); sq += __shfl_xor(sq, 2);
        float mean = s * (1.0f / 128.0f);
        float rstd = rsqrtf(sq * (1.0f / 128.0f) - mean * mean + 1e-5f);
        #pragma unroll
        for (int j = 0; j < 4; ++j) {
            bf16x8 o;
            #pragma unroll
            for (int e = 0; e < 8; ++e) {
                int ch = part * 32 + j * 8 + e;
                bf16 t = f2b((vals[j * 8 + e] - mean) * rstd * ln2g[ch] + ln2b[ch]);
                o[e] = *reinterpret_cast<__bf16*>(&t);
            }
            *reinterpret_cast<bf16x8*>(&sStage[row * 136 + part * 32 + j * 8]) = o;
        }
    }
    __syncthreads();   // last barrier: sStage(h2) visible to all; MLP is barrier-free

    // ---- barrier-free MLP: wave owns rows [wv*16, wv*16+16), full 512 hidden ----
    const bf16* sH2row = &sStage[(wv * 16 + mI) * 136];   // A-frag row base
    bf16* myP[2] = { &sP[wv][0][0], &sP[wv][1][0] };
    floatx4 acc2[8] = {};          // [ct2] -> out cols ct2*16+mI, rows q*4+r

    // prologue: bw1 frags for chunk 0
    bf16x8 bw1[4][2];
    #pragma unroll
    for (int ks = 0; ks < 4; ++ks)
        #pragma unroll
        for (int ct = 0; ct < 2; ++ct)
            bw1[ks][ct] = *reinterpret_cast<const bf16x8*>(
                w1T + (size_t)(ct * 16 + mI) * 128 + ks * 32 + q * 8);

    #pragma unroll 2
    for (int c = 0; c < 16; ++c) {
        bf16* strip = myP[c & 1];
        // GEMM1: h1[wave's 16 rows][c*32..+31]
        bf16x8 a1[4];
        #pragma unroll
        for (int ks = 0; ks < 4; ++ks)
            a1[ks] = *reinterpret_cast<const bf16x8*>(sH2row + ks * 32 + q * 8);
        floatx4 acc1[2] = {};
        #pragma unroll
        for (int ks = 0; ks < 4; ++ks)
            #pragma unroll
            for (int ct = 0; ct < 2; ++ct)
                acc1[ct] = MFMA(a1[ks], bw1[ks][ct], acc1[ct]);
        // issue GEMM2 B-frags now; latency hides under gelu
        bf16x8 bw2[8];
        #pragma unroll
        for (int ct2 = 0; ct2 < 8; ++ct2)
            bw2[ct2] = *reinterpret_cast<const bf16x8*>(
                w2T + (size_t)(ct2 * 16 + mI) * 512 + c * 32 + q * 8);
        // gelu -> private strip (transpose through wave-private LDS)
        float b1v0 = b1[c * 32 + mI], b1v1 = b1[c * 32 + 16 + mI];
        #pragma unroll
        for (int r = 0; r < 4; ++r) {
            strip[(q * 4 + r) * 40 + mI]      = f2b(gelu_exact(acc1[0][r] + b1v0));
            strip[(q * 4 + r) * 40 + 16 + mI] = f2b(gelu_exact(acc1[1][r] + b1v1));
        }
        // prefetch next chunk's bw1 (issued before the lgkm wait -> hidden)
        if (c < 15) {
            #pragma unroll
            for (int ks = 0; ks < 4; ++ks)
                #pragma unroll
                for (int ct = 0; ct < 2; ++ct)
                    bw1[ks][ct] = *reinterpret_cast<const bf16x8*>(
                        w1T + (size_t)((c + 1) * 32 + ct * 16 + mI) * 128 + ks * 32 + q * 8);
        }
        // wave-private visibility: drain LDS ops, order cross-lane read-after-write
        asm volatile("s_waitcnt lgkmcnt(0)" ::: "memory");
        // GEMM2 partial-K (32): A = h1 strip (row=mI, k=q*8)
        bf16x8 a2 = *reinterpret_cast<const bf16x8*>(&strip[mI * 40 + q * 8]);
        #pragma unroll
        for (int ct2 = 0; ct2 < 8; ++ct2)
            acc2[ct2] = MFMA(a2, bw2[ct2], acc2[ct2]);
    }

    // epilogue: out = acc2 + b2 + xres  (f32); wave writes only its own 16 rows
    #pragma unroll
    for (int ct2 = 0; ct2 < 8; ++ct2) {
        int col = ct2 * 16 + mI;
        float bs = b2[col];
        #pragma unroll
        for (int r = 0; r < 4; ++r) {
            int row = wv * 16 + q * 4 + r;
            out[(size_t)(bm + row) * 128 + col] =
                acc2[ct2][r] + bs + b2f(sXres[row * 136 + col]);
        }
    }
}

extern "C" void kernel_launch(void* const* d_in, const int* in_sizes, int n_in,
                              void* d_out, int out_size, void* d_ws, size_t ws_size,
                              hipStream_t stream)
{
    const float* x     = (const float*)d_in[0];
    const float* ln1g  = (const float*)d_in[1];
    const float* ln1b  = (const float*)d_in[2];
    const float* w_in  = (const float*)d_in[3];
    const float* b_in  = (const float*)d_in[4];
    const float* dw_k  = (const float*)d_in[5];
    const float* dw_b  = (const float*)d_in[6];
    const float* dwg   = (const float*)d_in[7];
    const float* dwb   = (const float*)d_in[8];
    const float* w_off = (const float*)d_in[9];
    const float* b_off = (const float*)d_in[10];
    const float* w_msk = (const float*)d_in[11];
    const float* b_msk = (const float*)d_in[12];
    const float* w_out = (const float*)d_in[13];
    const float* b_out = (const float*)d_in[14];
    const float* ln2g  = (const float*)d_in[15];
    const float* ln2b  = (const float*)d_in[16];
    const float* w1    = (const float*)d_in[17];
    const float* b1    = (const float*)d_in[18];
    const float* w2    = (const float*)d_in[19];
    const float* b2    = (const float*)d_in[20];
    float* out = (float*)d_out;

    // activations (bf16): xln(128)->ycore | xproj(128) | x1(128) | omr(216)
    bf16* ws = (bf16*)d_ws;
    bf16* xln   = ws;
    bf16* xproj = xln   + (size_t)NPIX * 128;
    bf16* x1    = xproj + (size_t)NPIX * 128;
    bf16* omr   = x1    + (size_t)NPIX * 128;
    bf16* ycore = xln;                  // xln dead after dwconv
    // bf16 transposed weights after activations (600/pix)
    bf16* wT    = ws + (size_t)NPIX * 600;
    bf16* w_inT  = wT;                  // 128x128
    bf16* w_omT  = w_inT  + 16384;      // 216x128 (off 144 + msk 72)
    bf16* w_outT = w_omT  + 27648;      // 128x128
    bf16* w1T    = w_outT + 16384;      // 512x128
    bf16* w2T    = w1T    + 65536;      // 128x512
    float* b_om  = (float*)(w2T + 65536);  // 216 f32
    const int WTOT = 191488 + 216;

    PrepArgs pa;
    pa.src[0] = w_in;  pa.dst[0] = w_inT;            pa.K[0] = 128; pa.N[0] = 128;
    pa.src[1] = w_off; pa.dst[1] = w_omT;            pa.K[1] = 128; pa.N[1] = 144;
    pa.src[2] = w_msk; pa.dst[2] = w_omT + 144*128;  pa.K[2] = 128; pa.N[2] = 72;
    pa.src[3] = w_out; pa.dst[3] = w_outT;           pa.K[3] = 128; pa.N[3] = 128;
    pa.src[4] = w1;    pa.dst[4] = w1T;              pa.K[4] = 128; pa.N[4] = 512;
    pa.src[5] = w2;    pa.dst[5] = w2T;              pa.K[5] = 512; pa.N[5] = 128;
    pa.cum[0] = 0;     pa.cum[1] = 16384;  pa.cum[2] = 34816; pa.cum[3] = 44032;
    pa.cum[4] = 60416; pa.cum[5] = 125952; pa.cum[6] = 191488;
    pa.b_off = b_off;  pa.b_msk = b_msk;   pa.b_om = b_om;

    const int M = NPIX;          // 36864
    dim3 blk(256);

    // 0. weight prep (+ bias concat)
    prep_weights<<<(WTOT + 255) / 256, blk, 0, stream>>>(pa, WTOT);
    // 1. xln = LN1(x)
    ln_kernel<float, bf16><<<NPIX / 4, blk, 0, stream>>>(x, ln1g, ln1b, xln);
    // 2. xproj = xln @ w_in + b_in
    gemm_mfma_kernel<<<dim3(2, M / 64), blk, 0, stream>>>(
        xln, w_inT, b_in, xproj, M, 128, 128);
    // 3. x1 = gelu(LN(dwconv(xln) + dw_b))
    dwconv_ln_gelu_kernel<<<NPIX / 4, blk, 0, stream>>>(xln, dw_k, dw_b, dwg, dwb, x1);
    // 4. omr = x1 @ [w_off | w_msk] + [b_off | b_msk]   (N=216 fused)
    gemm_mfma_kernel<<<dim3(4, M / 64), blk, 0, stream>>>(
        x1, w_omT, b_om, omr, M, 216, 128);
    // 5. ycore = dcnv3(xproj, omr)  [softmax fused in]
    dcn_core_kernel<<<NPIX / 4, blk, 0, stream>>>(xproj, omr, ycore);
    // 6-9. fused: outproj + residual + LN2 + barrier-free MLP + residual (v4)
    fused_tail_kernel<<<M / 64, blk, 0, stream>>>(
        ycore, x, w_outT, b_out, ln2g, ln2b, w1T, b1, w2T, b2, out);
}

// Round 3
// 254.675 us; speedup vs baseline: 1.1467x; 1.1467x over previous
//
#include <hip/hip_runtime.h>
#include <hip/hip_bf16.h>
#include <math.h>

using bf16 = __hip_bfloat16;
using bf162 = __hip_bfloat162;

typedef __bf16 bf16x8 __attribute__((ext_vector_type(8)));
typedef float floatx4 __attribute__((ext_vector_type(4)));

constexpr int NB = 4, HH = 96, WW = 96, CC = 128, GG = 8, PP = 9;
constexpr int HW = HH * WW;          // 9216
constexpr int NPIX = NB * HW;        // 36864

__device__ __forceinline__ float ld1(const float* p) { return *p; }
__device__ __forceinline__ float ld1(const bf16* p)  { return __bfloat162float(*p); }
__device__ __forceinline__ void st1(float* p, float v) { *p = v; }
__device__ __forceinline__ void st1(bf16* p, float v)  { *p = __float2bfloat16(v); }
__device__ __forceinline__ float b2f(bf16 v) { return __bfloat162float(v); }
__device__ __forceinline__ bf16 f2b(float v) { return __float2bfloat16(v); }
__device__ __forceinline__ float gelu_exact(float v) {
    return 0.5f * v * (1.0f + erff(v * 0.7071067811865475f));
}
__device__ __forceinline__ floatx4 MFMA(bf16x8 a, bf16x8 b, floatx4 c) {
    return __builtin_amdgcn_mfma_f32_16x16x32_bf16(a, b, c, 0, 0, 0);
}

// ---------------- one-time weight prep: f32 W[K][N] -> bf16 Wt[N][K] (+ bias concat)
struct PrepArgs {
    const float* src[6];
    bf16* dst[6];
    int K[6], N[6];
    int cum[7];
    const float* b_off; const float* b_msk; float* b_om;   // bias concat 216
};

__global__ __launch_bounds__(256) void prep_weights(PrepArgs pa, int total)
{
    int t = blockIdx.x * 256 + threadIdx.x;
    if (t >= total) return;
    if (t >= pa.cum[6]) {                 // bias concat tail
        int e = t - pa.cum[6];
        pa.b_om[e] = (e < 144) ? pa.b_off[e] : pa.b_msk[e - 144];
        return;
    }
    int i = 0;
    #pragma unroll
    for (int j = 0; j < 5; ++j) if (t >= pa.cum[j + 1]) i = j + 1;
    int e = t - pa.cum[i];
    int Ki = pa.K[i], Ni = pa.N[i];
    int n = e / Ki, k = e - n * Ki;
    pa.dst[i][e] = f2b(pa.src[i][(size_t)k * Ni + n]);
}

// ---------------- LayerNorm over C=128, one wave per pixel, 2 ch/lane
template<typename TI, typename TO>
__global__ __launch_bounds__(256) void ln_kernel(
    const TI* __restrict__ X, const float* __restrict__ g,
    const float* __restrict__ b, TO* __restrict__ out)
{
    int wave = (blockIdx.x * 256 + threadIdx.x) >> 6;
    int lane = threadIdx.x & 63;
    if (wave >= NPIX) return;
    const TI* xp = X + (size_t)wave * 128 + 2 * lane;
    float v0 = ld1(xp), v1 = ld1(xp + 1);
    float s = v0 + v1, q = v0 * v0 + v1 * v1;
    #pragma unroll
    for (int o = 32; o; o >>= 1) { s += __shfl_xor(s, o); q += __shfl_xor(q, o); }
    float mean = s * (1.0f / 128.0f);
    float rstd = rsqrtf(q * (1.0f / 128.0f) - mean * mean + 1e-5f);
    float g0 = g[2 * lane], g1 = g[2 * lane + 1];
    float b0 = b[2 * lane], b1 = b[2 * lane + 1];
    TO* op = out + (size_t)wave * 128 + 2 * lane;
    st1(op,     (v0 - mean) * rstd * g0 + b0);
    st1(op + 1, (v1 - mean) * rstd * g1 + b1);
}

// ---------------- depthwise 3x3 conv (SAME, zero pad) + LN + exact GELU. wave/pixel
__global__ __launch_bounds__(256) void dwconv_ln_gelu_kernel(
    const bf16* __restrict__ xln, const float* __restrict__ dwk,
    const float* __restrict__ dwb, const float* __restrict__ gam,
    const float* __restrict__ bet, bf16* __restrict__ out)
{
    int wave = (blockIdx.x * 256 + threadIdx.x) >> 6;
    int lane = threadIdx.x & 63;
    if (wave >= NPIX) return;
    int n = wave / HW; int rem = wave % HW;
    int y = rem / WW;  int x = rem % WW;
    const bf162* xp = (const bf162*)xln;
    float a0 = 0.f, a1 = 0.f;
    #pragma unroll
    for (int ky = 0; ky < 3; ++ky) {
        int yy = y + ky - 1;
        if (yy < 0 || yy >= HH) continue;
        #pragma unroll
        for (int kx = 0; kx < 3; ++kx) {
            int xx = x + kx - 1;
            if (xx < 0 || xx >= WW) continue;
            bf162 v = xp[((size_t)(n * HH + yy) * WW + xx) * 64 + lane];
            const float* w = dwk + (ky * 3 + kx) * CC + 2 * lane;
            a0 = fmaf(b2f(v.x), w[0], a0);
            a1 = fmaf(b2f(v.y), w[1], a1);
        }
    }
    a0 += dwb[2 * lane]; a1 += dwb[2 * lane + 1];
    float s = a0 + a1, q = a0 * a0 + a1 * a1;
    #pragma unroll
    for (int o = 32; o; o >>= 1) { s += __shfl_xor(s, o); q += __shfl_xor(q, o); }
    float mean = s * (1.0f / 128.0f);
    float rstd = rsqrtf(q * (1.0f / 128.0f) - mean * mean + 1e-5f);
    float h0 = gelu_exact((a0 - mean) * rstd * gam[2 * lane]     + bet[2 * lane]);
    float h1 = gelu_exact((a1 - mean) * rstd * gam[2 * lane + 1] + bet[2 * lane + 1]);
    bf162 o2; o2.x = f2b(h0); o2.y = f2b(h1);
    ((bf162*)out)[(size_t)wave * 64 + lane] = o2;
}

// ---------------- DCNv3 core: wave per pixel, fused mask-softmax + two-phase
__global__ __launch_bounds__(256) void dcn_core_kernel(
    const bf16* __restrict__ xproj, const bf16* __restrict__ omr,
    bf16* __restrict__ out)
{
    __shared__ int4   sOff[4][72];
    __shared__ float4 sW[4][72];
    __shared__ float  sRaw[4][72];
    int wv = threadIdx.x >> 6;
    int lane = threadIdx.x & 63;
    int pix = blockIdx.x * 4 + wv;
    int n = pix / HW; int rem = pix % HW;
    int iy = rem / WW; int ix = rem % WW;
    const bf16* om = omr + (size_t)pix * 216;

    for (int e = lane; e < 72; e += 64)
        sRaw[wv][e] = b2f(om[144 + e]);
    __syncthreads();

    for (int e = lane; e < 72; e += 64) {
        int g = e / 9, p = e - 9 * g;
        float mx = -1e30f;
        #pragma unroll
        for (int i = 0; i < 9; ++i) mx = fmaxf(mx, sRaw[wv][g * 9 + i]);
        float ssum = 0.f;
        #pragma unroll
        for (int i = 0; i < 9; ++i) ssum += __expf(sRaw[wv][g * 9 + i] - mx);
        float mw = __expf(sRaw[wv][e] - mx) / ssum;

        float ox = b2f(om[g * 18 + 2 * p]);
        float oy = b2f(om[g * 18 + 2 * p + 1]);
        int kx = p / 3 - 1, ky = p % 3 - 1;  // torch meshgrid 'ij': x slowest
        float px = (float)(ix + kx) + ox;
        float py = (float)(iy + ky) + oy;
        float fx0 = floorf(px), fy0 = floorf(py);
        int x0 = (int)fx0, y0 = (int)fy0;
        float fx = px - fx0, fy = py - fy0;
        bool vx0 = (x0 >= 0) & (x0 < WW), vx1 = (x0 + 1 >= 0) & (x0 + 1 < WW);
        bool vy0 = (y0 >= 0) & (y0 < HH), vy1 = (y0 + 1 >= 0) & (y0 + 1 < HH);
        float w00 = (1.f - fy) * (1.f - fx) * mw * (vy0 && vx0 ? 1.f : 0.f);
        float w01 = (1.f - fy) * fx         * mw * (vy0 && vx1 ? 1.f : 0.f);
        float w10 = fy * (1.f - fx)         * mw * (vy1 && vx0 ? 1.f : 0.f);
        float w11 = fy * fx                 * mw * (vy1 && vx1 ? 1.f : 0.f);
        int x0c = min(max(x0, 0), WW - 1), x1c = min(max(x0 + 1, 0), WW - 1);
        int y0c = min(max(y0, 0), HH - 1), y1c = min(max(y0 + 1, 0), HH - 1);
        sOff[wv][e] = make_int4((y0c * WW + x0c) * CC, (y0c * WW + x1c) * CC,
                                (y1c * WW + x0c) * CC, (y1c * WW + x1c) * CC);
        sW[wv][e] = make_float4(w00, w01, w10, w11);
    }
    __syncthreads();

    const bf16* xb = xproj + (size_t)n * HW * CC + 2 * lane;
    int gbase = (lane >> 3) * 9;
    float a0 = 0.f, a1 = 0.f;
    #pragma unroll
    for (int p = 0; p < 9; ++p) {
        int4 o = sOff[wv][gbase + p];
        float4 w = sW[wv][gbase + p];
        bf162 v00 = *(const bf162*)(xb + o.x);
        bf162 v01 = *(const bf162*)(xb + o.y);
        bf162 v10 = *(const bf162*)(xb + o.z);
        bf162 v11 = *(const bf162*)(xb + o.w);
        a0 += w.x * b2f(v00.x) + w.y * b2f(v01.x) + w.z * b2f(v10.x) + w.w * b2f(v11.x);
        a1 += w.x * b2f(v00.y) + w.y * b2f(v01.y) + w.z * b2f(v10.y) + w.w * b2f(v11.y);
    }
    bf162 o2; o2.x = f2b(a0); o2.y = f2b(a1);
    ((bf162*)out)[(size_t)pix * 64 + lane] = o2;
}

// ---------------- MFMA GEMM (R3-proven): Out[M,N] = A[M,K] @ Wt^T + bias
__global__ __launch_bounds__(256) void gemm_mfma_kernel(
    const bf16* __restrict__ A, const bf16* __restrict__ Wt,
    const float* __restrict__ bias, bf16* __restrict__ Out, int M, int Nn, int K)
{
    __shared__ __align__(16) __bf16 As[64][72];
    __shared__ __align__(16) __bf16 Bs[64][72];
    int tid = threadIdx.x;
    int wv = tid >> 6, lane = tid & 63;
    int bm = blockIdx.y * 64, bn = blockIdx.x * 64;
    int mI = lane & 15, q = lane >> 4;
    floatx4 acc[4] = {};

    for (int k0 = 0; k0 < K; k0 += 64) {
        #pragma unroll
        for (int cc = 0; cc < 2; ++cc) {
            int ch = tid * 2 + cc;               // 0..511
            int row = ch >> 3, ko = (ch & 7) * 8;
            *reinterpret_cast<uint4*>(&As[row][ko]) =
                *reinterpret_cast<const uint4*>(A + (size_t)(bm + row) * K + k0 + ko);
            int ng = bn + row;
            uint4 bv = make_uint4(0, 0, 0, 0);
            if (ng < Nn) bv = *reinterpret_cast<const uint4*>(Wt + (size_t)ng * K + k0 + ko);
            *reinterpret_cast<uint4*>(&Bs[row][ko]) = bv;
        }
        __syncthreads();
        #pragma unroll
        for (int kk = 0; kk < 64; kk += 32) {
            bf16x8 a = *reinterpret_cast<const bf16x8*>(&As[wv * 16 + mI][kk + q * 8]);
            #pragma unroll
            for (int t = 0; t < 4; ++t) {
                bf16x8 b = *reinterpret_cast<const bf16x8*>(&Bs[t * 16 + mI][kk + q * 8]);
                acc[t] = MFMA(a, b, acc[t]);
            }
        }
        __syncthreads();
    }
    int row0 = bm + wv * 16 + q * 4;
    #pragma unroll
    for (int t = 0; t < 4; ++t) {
        int col = bn + t * 16 + mI;
        if (col >= Nn) continue;
        float bs = bias[col];
        #pragma unroll
        for (int r = 0; r < 4; ++r)
            st1(Out + (size_t)(row0 + r) * Nn + col, acc[t][r] + bs);
    }
}

// ---------------- fused tail, v5: v2 structure with the barrier chain thinned.
// R2 post-mortem: v4's wave-private MLP serialized (asm clobber/chunk) + 4x
// weight traffic -> 107us. v5 returns to v2's proven cross-wave split (166MB
// L2 weights) and removes barriers incrementally: (a) xres in REGISTERS (acc0
// and acc2 have the identical thread->element map) -> sXres buffer gone, 1
// barrier gone; (b) LN2 stats by in-wave shfl_xor over mI + 2KB cross-wave
// partial table (1 barrier); (c) h1 double-buffer (LDS freed by sXres) drops
// the per-phase WAR barrier: 4 phases x 1 sync. 11 -> 7 barriers. LDS still
// 52.2KB -> 3 blocks/CU. No inline asm, compiler schedules freely.
__global__ __launch_bounds__(256, 3) void fused_tail_kernel(
    const bf16* __restrict__ ycore, const float* __restrict__ x,
    const bf16* __restrict__ w_outT, const float* __restrict__ b_out,
    const float* __restrict__ ln2g, const float* __restrict__ ln2b,
    const bf16* __restrict__ w1T, const float* __restrict__ b1,
    const bf16* __restrict__ w2T, const float* __restrict__ b2,
    float* __restrict__ out)
{
    __shared__ __align__(16) bf16 sStage[64 * 136];    // ycore tile -> h2 (LN2 out)
    __shared__ __align__(16) bf16 sH1[2][64 * 136];    // h1 ping-pong phase buffers
    // LN partial table [64 rows][4 waves][sum,sq] overlaps sH1[1]: reads finish
    // before barrier B3; sH1[1] first written in phase 1 (after phase-0 sync).
    float* sLN = (float*)&sH1[1][0];                   // 64*8 floats = 2KB

    int tid = threadIdx.x, wv = tid >> 6, lane = tid & 63;
    int mI = lane & 15, q = lane >> 4;
    int bm = blockIdx.x * 64;

    // prefetch GEMM0 B-frags (8 independent 16B loads, in flight during staging)
    bf16x8 bw0[4][2];
    #pragma unroll
    for (int ks = 0; ks < 4; ++ks)
        #pragma unroll
        for (int ct = 0; ct < 2; ++ct)
            bw0[ks][ct] = *reinterpret_cast<const bf16x8*>(
                w_outT + (size_t)(wv * 32 + ct * 16 + mI) * 128 + ks * 32 + q * 8);

    // stage ycore tile (64 x 128) at stride 136
    #pragma unroll
    for (int i = 0; i < 4; ++i) {
        int s = tid + 256 * i;
        int row = s >> 4, ko = (s & 15) * 8;
        *reinterpret_cast<uint4*>(&sStage[row * 136 + ko]) =
            *reinterpret_cast<const uint4*>(ycore + (size_t)(bm + row) * 128 + ko);
    }
    __syncthreads();                                   // B1

    // GEMM0: wave covers out-proj cols wv*32..+31 over all 64 rows
    floatx4 acc0[4][2] = {};
    #pragma unroll
    for (int ks = 0; ks < 4; ++ks) {
        int k = ks * 32 + q * 8;
        bf16x8 a[4];
        #pragma unroll
        for (int rt = 0; rt < 4; ++rt)
            a[rt] = *reinterpret_cast<const bf16x8*>(&sStage[(rt * 16 + mI) * 136 + k]);
        #pragma unroll
        for (int ct = 0; ct < 2; ++ct)
            #pragma unroll
            for (int rt = 0; rt < 4; ++rt)
                acc0[rt][ct] = MFMA(a[rt], bw0[ks][ct], acc0[rt][ct]);
    }

    // xres in registers + per-row LN partial sums (sum over this wave's 32 cols)
    float xr[4][2][4];
    float psum[4][4], psq[4][4];                       // [rt][r]
    #pragma unroll
    for (int rt = 0; rt < 4; ++rt)
        #pragma unroll
        for (int r = 0; r < 4; ++r) {
            int row = rt * 16 + q * 4 + r;
            float v0 = acc0[rt][0][r] + b_out[wv * 32 + mI]
                     + x[(size_t)(bm + row) * 128 + wv * 32 + mI];
            float v1 = acc0[rt][1][r] + b_out[wv * 32 + 16 + mI]
                     + x[(size_t)(bm + row) * 128 + wv * 32 + 16 + mI];
            xr[rt][0][r] = v0; xr[rt][1][r] = v1;
            psum[rt][r] = v0 + v1;
            psq[rt][r]  = v0 * v0 + v1 * v1;
        }
    // intra-wave reduce across mI (16-lane groups; q preserved)
    #pragma unroll
    for (int o = 1; o < 16; o <<= 1)
        #pragma unroll
        for (int rt = 0; rt < 4; ++rt)
            #pragma unroll
            for (int r = 0; r < 4; ++r) {
                psum[rt][r] += __shfl_xor(psum[rt][r], o);
                psq[rt][r]  += __shfl_xor(psq[rt][r], o);
            }
    if (mI == 0) {
        #pragma unroll
        for (int rt = 0; rt < 4; ++rt)
            #pragma unroll
            for (int r = 0; r < 4; ++r) {
                int row = rt * 16 + q * 4 + r;
                sLN[row * 8 + wv * 2]     = psum[rt][r];
                sLN[row * 8 + wv * 2 + 1] = psq[rt][r];
            }
    }
    __syncthreads();                                   // B2 (also fences GEMM0 sStage reads)

    // stats + normalize + write h2 into sStage (overwrite safe post-B2)
    {
        float g0 = ln2g[wv * 32 + mI],      g1 = ln2g[wv * 32 + 16 + mI];
        float be0 = ln2b[wv * 32 + mI],     be1 = ln2b[wv * 32 + 16 + mI];
        #pragma unroll
        for (int rt = 0; rt < 4; ++rt)
            #pragma unroll
            for (int r = 0; r < 4; ++r) {
                int row = rt * 16 + q * 4 + r;
                float4 p0 = *reinterpret_cast<float4*>(&sLN[row * 8]);
                float4 p1 = *reinterpret_cast<float4*>(&sLN[row * 8 + 4]);
                float s  = p0.x + p0.z + p1.x + p1.z;
                float sq = p0.y + p0.w + p1.y + p1.w;
                float mean = s * (1.0f / 128.0f);
                float rstd = rsqrtf(sq * (1.0f / 128.0f) - mean * mean + 1e-5f);
                sStage[row * 136 + wv * 32 + mI] =
                    f2b((xr[rt][0][r] - mean) * rstd * g0 + be0);
                sStage[row * 136 + wv * 32 + 16 + mI] =
                    f2b((xr[rt][1][r] - mean) * rstd * g1 + be1);
            }
    }
    __syncthreads();                                   // B3: h2 visible to all waves

    // MLP in four 128-col phases over hidden; ONE barrier per phase (h1 dbuf)
    floatx4 acc2[4][2] = {};
    bf16x8 bw1[4][2];
    #pragma unroll
    for (int ks = 0; ks < 4; ++ks)
        #pragma unroll
        for (int ct = 0; ct < 2; ++ct)
            bw1[ks][ct] = *reinterpret_cast<const bf16x8*>(
                w1T + (size_t)(wv * 32 + ct * 16 + mI) * 128 + ks * 32 + q * 8);

    #pragma unroll 1
    for (int ph = 0; ph < 4; ++ph) {
        bf16* buf = (ph & 1) ? &sH1[1][0] : &sH1[0][0];
        // GEMM1: h1 cols (ph*128 + wv*32..+31), A from sStage (h2)
        floatx4 acc1[4][2] = {};
        #pragma unroll
        for (int ks = 0; ks < 4; ++ks) {
            int k = ks * 32 + q * 8;
            bf16x8 a[4];
            #pragma unroll
            for (int rt = 0; rt < 4; ++rt)
                a[rt] = *reinterpret_cast<const bf16x8*>(&sStage[(rt * 16 + mI) * 136 + k]);
            #pragma unroll
            for (int ct = 0; ct < 2; ++ct)
                #pragma unroll
                for (int rt = 0; rt < 4; ++rt)
                    acc1[rt][ct] = MFMA(a[rt], bw1[ks][ct], acc1[rt][ct]);
        }
        // hoist GEMM2 B-frags; they fly during the gelu VALU burst
        bf16x8 bw2[4][2];
        #pragma unroll
        for (int ks = 0; ks < 4; ++ks)
            #pragma unroll
            for (int ct = 0; ct < 2; ++ct)
                bw2[ks][ct] = *reinterpret_cast<const bf16x8*>(
                    w2T + (size_t)(wv * 32 + ct * 16 + mI) * 512 + ph * 128 + ks * 32 + q * 8);
        // gelu -> buf (h1 phase slice, local cols wv*32..+31)
        #pragma unroll
        for (int rt = 0; rt < 4; ++rt)
            #pragma unroll
            for (int ct = 0; ct < 2; ++ct) {
                int lcol = wv * 32 + ct * 16 + mI;
                float bs = b1[ph * 128 + lcol];
                #pragma unroll
                for (int r = 0; r < 4; ++r) {
                    int row = rt * 16 + q * 4 + r;
                    buf[row * 136 + lcol] = f2b(gelu_exact(acc1[rt][ct][r] + bs));
                }
            }
        // prefetch next phase's bw1 before the barrier
        if (ph < 3) {
            #pragma unroll
            for (int ks = 0; ks < 4; ++ks)
                #pragma unroll
                for (int ct = 0; ct < 2; ++ct)
                    bw1[ks][ct] = *reinterpret_cast<const bf16x8*>(
                        w1T + (size_t)((ph + 1) * 128 + wv * 32 + ct * 16 + mI) * 128
                            + ks * 32 + q * 8);
        }
        __syncthreads();   // B4..B7: buf complete; also licenses overwrite of buf^1
        // GEMM2 partial-K (128): A from buf
        #pragma unroll
        for (int ks = 0; ks < 4; ++ks) {
            int k = ks * 32 + q * 8;
            bf16x8 a[4];
            #pragma unroll
            for (int rt = 0; rt < 4; ++rt)
                a[rt] = *reinterpret_cast<const bf16x8*>(&buf[(rt * 16 + mI) * 136 + k]);
            #pragma unroll
            for (int ct = 0; ct < 2; ++ct)
                #pragma unroll
                for (int rt = 0; rt < 4; ++rt)
                    acc2[rt][ct] = MFMA(a[rt], bw2[ks][ct], acc2[rt][ct]);
        }
    }
    // epilogue: out = acc2 + b2 + xres (registers; same thread->element map)
    #pragma unroll
    for (int rt = 0; rt < 4; ++rt)
        #pragma unroll
        for (int ct = 0; ct < 2; ++ct) {
            int col = wv * 32 + ct * 16 + mI;
            float bs = b2[col];
            #pragma unroll
            for (int r = 0; r < 4; ++r) {
                int row = rt * 16 + q * 4 + r;
                out[(size_t)(bm + row) * 128 + col] =
                    acc2[rt][ct][r] + bs + xr[rt][ct][r];
            }
        }
}

extern "C" void kernel_launch(void* const* d_in, const int* in_sizes, int n_in,
                              void* d_out, int out_size, void* d_ws, size_t ws_size,
                              hipStream_t stream)
{
    const float* x     = (const float*)d_in[0];
    const float* ln1g  = (const float*)d_in[1];
    const float* ln1b  = (const float*)d_in[2];
    const float* w_in  = (const float*)d_in[3];
    const float* b_in  = (const float*)d_in[4];
    const float* dw_k  = (const float*)d_in[5];
    const float* dw_b  = (const float*)d_in[6];
    const float* dwg   = (const float*)d_in[7];
    const float* dwb   = (const float*)d_in[8];
    const float* w_off = (const float*)d_in[9];
    const float* b_off = (const float*)d_in[10];
    const float* w_msk = (const float*)d_in[11];
    const float* b_msk = (const float*)d_in[12];
    const float* w_out = (const float*)d_in[13];
    const float* b_out = (const float*)d_in[14];
    const float* ln2g  = (const float*)d_in[15];
    const float* ln2b  = (const float*)d_in[16];
    const float* w1    = (const float*)d_in[17];
    const float* b1    = (const float*)d_in[18];
    const float* w2    = (const float*)d_in[19];
    const float* b2    = (const float*)d_in[20];
    float* out = (float*)d_out;

    // activations (bf16): xln(128)->ycore | xproj(128) | x1(128) | omr(216)
    bf16* ws = (bf16*)d_ws;
    bf16* xln   = ws;
    bf16* xproj = xln   + (size_t)NPIX * 128;
    bf16* x1    = xproj + (size_t)NPIX * 128;
    bf16* omr   = x1    + (size_t)NPIX * 128;
    bf16* ycore = xln;                  // xln dead after dwconv
    // bf16 transposed weights after activations (600/pix)
    bf16* wT    = ws + (size_t)NPIX * 600;
    bf16* w_inT  = wT;                  // 128x128
    bf16* w_omT  = w_inT  + 16384;      // 216x128 (off 144 + msk 72)
    bf16* w_outT = w_omT  + 27648;      // 128x128
    bf16* w1T    = w_outT + 16384;      // 512x128
    bf16* w2T    = w1T    + 65536;      // 128x512
    float* b_om  = (float*)(w2T + 65536);  // 216 f32
    const int WTOT = 191488 + 216;

    PrepArgs pa;
    pa.src[0] = w_in;  pa.dst[0] = w_inT;            pa.K[0] = 128; pa.N[0] = 128;
    pa.src[1] = w_off; pa.dst[1] = w_omT;            pa.K[1] = 128; pa.N[1] = 144;
    pa.src[2] = w_msk; pa.dst[2] = w_omT + 144*128;  pa.K[2] = 128; pa.N[2] = 72;
    pa.src[3] = w_out; pa.dst[3] = w_outT;           pa.K[3] = 128; pa.N[3] = 128;
    pa.src[4] = w1;    pa.dst[4] = w1T;              pa.K[4] = 128; pa.N[4] = 512;
    pa.src[5] = w2;    pa.dst[5] = w2T;              pa.K[5] = 512; pa.N[5] = 128;
    pa.cum[0] = 0;     pa.cum[1] = 16384;  pa.cum[2] = 34816; pa.cum[3] = 44032;
    pa.cum[4] = 60416; pa.cum[5] = 125952; pa.cum[6] = 191488;
    pa.b_off = b_off;  pa.b_msk = b_msk;   pa.b_om = b_om;

    const int M = NPIX;          // 36864
    dim3 blk(256);

    // 0. weight prep (+ bias concat)
    prep_weights<<<(WTOT + 255) / 256, blk, 0, stream>>>(pa, WTOT);
    // 1. xln = LN1(x)
    ln_kernel<float, bf16><<<NPIX / 4, blk, 0, stream>>>(x, ln1g, ln1b, xln);
    // 2. xproj = xln @ w_in + b_in
    gemm_mfma_kernel<<<dim3(2, M / 64), blk, 0, stream>>>(
        xln, w_inT, b_in, xproj, M, 128, 128);
    // 3. x1 = gelu(LN(dwconv(xln) + dw_b))
    dwconv_ln_gelu_kernel<<<NPIX / 4, blk, 0, stream>>>(xln, dw_k, dw_b, dwg, dwb, x1);
    // 4. omr = x1 @ [w_off | w_msk] + [b_off | b_msk]   (N=216 fused)
    gemm_mfma_kernel<<<dim3(4, M / 64), blk, 0, stream>>>(
        x1, w_omT, b_om, omr, M, 216, 128);
    // 5. ycore = dcnv3(xproj, omr)  [softmax fused in]
    dcn_core_kernel<<<NPIX / 4, blk, 0, stream>>>(xproj, omr, ycore);
    // 6-9. fused: outproj + residual + LN2 + MLP + residual  (v5: 7 barriers)
    fused_tail_kernel<<<M / 64, blk, 0, stream>>>(
        ycore, x, w_outT, b_out, ln2g, ln2b, w1T, b1, w2T, b2, out);
}

// Round 4
// 238.787 us; speedup vs baseline: 1.2230x; 1.0665x over previous
//
#include <hip/hip_runtime.h>
#include <hip/hip_bf16.h>
#include <math.h>

using bf16 = __hip_bfloat16;
using bf162 = __hip_bfloat162;

typedef __bf16 bf16x8 __attribute__((ext_vector_type(8)));
typedef float floatx4 __attribute__((ext_vector_type(4)));

constexpr int NB = 4, HH = 96, WW = 96, CC = 128, GG = 8, PP = 9;
constexpr int HW = HH * WW;          // 9216
constexpr int NPIX = NB * HW;        // 36864

__device__ __forceinline__ float ld1(const float* p) { return *p; }
__device__ __forceinline__ float ld1(const bf16* p)  { return __bfloat162float(*p); }
__device__ __forceinline__ void st1(float* p, float v) { *p = v; }
__device__ __forceinline__ void st1(bf16* p, float v)  { *p = __float2bfloat16(v); }
__device__ __forceinline__ float b2f(bf16 v) { return __bfloat162float(v); }
__device__ __forceinline__ bf16 f2b(float v) { return __float2bfloat16(v); }
__device__ __forceinline__ float gelu_exact(float v) {
    return 0.5f * v * (1.0f + erff(v * 0.7071067811865475f));
}
__device__ __forceinline__ floatx4 MFMA(bf16x8 a, bf16x8 b, floatx4 c) {
    return __builtin_amdgcn_mfma_f32_16x16x32_bf16(a, b, c, 0, 0, 0);
}

// ---------------- one-time weight prep: f32 W[K][N] -> bf16 Wt[N][K] (+ bias concat)
struct PrepArgs {
    const float* src[6];
    bf16* dst[6];
    int K[6], N[6];
    int cum[7];
    const float* b_off; const float* b_msk; float* b_om;   // bias concat 216
};

__global__ __launch_bounds__(256) void prep_weights(PrepArgs pa, int total)
{
    int t = blockIdx.x * 256 + threadIdx.x;
    if (t >= total) return;
    if (t >= pa.cum[6]) {                 // bias concat tail
        int e = t - pa.cum[6];
        pa.b_om[e] = (e < 144) ? pa.b_off[e] : pa.b_msk[e - 144];
        return;
    }
    int i = 0;
    #pragma unroll
    for (int j = 0; j < 5; ++j) if (t >= pa.cum[j + 1]) i = j + 1;
    int e = t - pa.cum[i];
    int Ki = pa.K[i], Ni = pa.N[i];
    int n = e / Ki, k = e - n * Ki;
    pa.dst[i][e] = f2b(pa.src[i][(size_t)k * Ni + n]);
}

// ---------------- LayerNorm over C=128, one wave per pixel, 2 ch/lane
template<typename TI, typename TO>
__global__ __launch_bounds__(256) void ln_kernel(
    const TI* __restrict__ X, const float* __restrict__ g,
    const float* __restrict__ b, TO* __restrict__ out)
{
    int wave = (blockIdx.x * 256 + threadIdx.x) >> 6;
    int lane = threadIdx.x & 63;
    if (wave >= NPIX) return;
    const TI* xp = X + (size_t)wave * 128 + 2 * lane;
    float v0 = ld1(xp), v1 = ld1(xp + 1);
    float s = v0 + v1, q = v0 * v0 + v1 * v1;
    #pragma unroll
    for (int o = 32; o; o >>= 1) { s += __shfl_xor(s, o); q += __shfl_xor(q, o); }
    float mean = s * (1.0f / 128.0f);
    float rstd = rsqrtf(q * (1.0f / 128.0f) - mean * mean + 1e-5f);
    float g0 = g[2 * lane], g1 = g[2 * lane + 1];
    float b0 = b[2 * lane], b1 = b[2 * lane + 1];
    TO* op = out + (size_t)wave * 128 + 2 * lane;
    st1(op,     (v0 - mean) * rstd * g0 + b0);
    st1(op + 1, (v1 - mean) * rstd * g1 + b1);
}

// ---------------- depthwise 3x3 conv (SAME, zero pad) + LN + exact GELU. wave/pixel
__global__ __launch_bounds__(256) void dwconv_ln_gelu_kernel(
    const bf16* __restrict__ xln, const float* __restrict__ dwk,
    const float* __restrict__ dwb, const float* __restrict__ gam,
    const float* __restrict__ bet, bf16* __restrict__ out)
{
    int wave = (blockIdx.x * 256 + threadIdx.x) >> 6;
    int lane = threadIdx.x & 63;
    if (wave >= NPIX) return;
    int n = wave / HW; int rem = wave % HW;
    int y = rem / WW;  int x = rem % WW;
    const bf162* xp = (const bf162*)xln;
    float a0 = 0.f, a1 = 0.f;
    #pragma unroll
    for (int ky = 0; ky < 3; ++ky) {
        int yy = y + ky - 1;
        if (yy < 0 || yy >= HH) continue;
        #pragma unroll
        for (int kx = 0; kx < 3; ++kx) {
            int xx = x + kx - 1;
            if (xx < 0 || xx >= WW) continue;
            bf162 v = xp[((size_t)(n * HH + yy) * WW + xx) * 64 + lane];
            const float* w = dwk + (ky * 3 + kx) * CC + 2 * lane;
            a0 = fmaf(b2f(v.x), w[0], a0);
            a1 = fmaf(b2f(v.y), w[1], a1);
        }
    }
    a0 += dwb[2 * lane]; a1 += dwb[2 * lane + 1];
    float s = a0 + a1, q = a0 * a0 + a1 * a1;
    #pragma unroll
    for (int o = 32; o; o >>= 1) { s += __shfl_xor(s, o); q += __shfl_xor(q, o); }
    float mean = s * (1.0f / 128.0f);
    float rstd = rsqrtf(q * (1.0f / 128.0f) - mean * mean + 1e-5f);
    float h0 = gelu_exact((a0 - mean) * rstd * gam[2 * lane]     + bet[2 * lane]);
    float h1 = gelu_exact((a1 - mean) * rstd * gam[2 * lane + 1] + bet[2 * lane + 1]);
    bf162 o2; o2.x = f2b(h0); o2.y = f2b(h1);
    ((bf162*)out)[(size_t)wave * 64 + lane] = o2;
}

// ---------------- DCNv3 core: wave per pixel, fused mask-softmax + two-phase
__global__ __launch_bounds__(256) void dcn_core_kernel(
    const bf16* __restrict__ xproj, const bf16* __restrict__ omr,
    bf16* __restrict__ out)
{
    __shared__ int4   sOff[4][72];
    __shared__ float4 sW[4][72];
    __shared__ float  sRaw[4][72];
    int wv = threadIdx.x >> 6;
    int lane = threadIdx.x & 63;
    int pix = blockIdx.x * 4 + wv;
    int n = pix / HW; int rem = pix % HW;
    int iy = rem / WW; int ix = rem % WW;
    const bf16* om = omr + (size_t)pix * 216;

    for (int e = lane; e < 72; e += 64)
        sRaw[wv][e] = b2f(om[144 + e]);
    __syncthreads();

    for (int e = lane; e < 72; e += 64) {
        int g = e / 9, p = e - 9 * g;
        float mx = -1e30f;
        #pragma unroll
        for (int i = 0; i < 9; ++i) mx = fmaxf(mx, sRaw[wv][g * 9 + i]);
        float ssum = 0.f;
        #pragma unroll
        for (int i = 0; i < 9; ++i) ssum += __expf(sRaw[wv][g * 9 + i] - mx);
        float mw = __expf(sRaw[wv][e] - mx) / ssum;

        float ox = b2f(om[g * 18 + 2 * p]);
        float oy = b2f(om[g * 18 + 2 * p + 1]);
        int kx = p / 3 - 1, ky = p % 3 - 1;  // torch meshgrid 'ij': x slowest
        float px = (float)(ix + kx) + ox;
        float py = (float)(iy + ky) + oy;
        float fx0 = floorf(px), fy0 = floorf(py);
        int x0 = (int)fx0, y0 = (int)fy0;
        float fx = px - fx0, fy = py - fy0;
        bool vx0 = (x0 >= 0) & (x0 < WW), vx1 = (x0 + 1 >= 0) & (x0 + 1 < WW);
        bool vy0 = (y0 >= 0) & (y0 < HH), vy1 = (y0 + 1 >= 0) & (y0 + 1 < HH);
        float w00 = (1.f - fy) * (1.f - fx) * mw * (vy0 && vx0 ? 1.f : 0.f);
        float w01 = (1.f - fy) * fx         * mw * (vy0 && vx1 ? 1.f : 0.f);
        float w10 = fy * (1.f - fx)         * mw * (vy1 && vx0 ? 1.f : 0.f);
        float w11 = fy * fx                 * mw * (vy1 && vx1 ? 1.f : 0.f);
        int x0c = min(max(x0, 0), WW - 1), x1c = min(max(x0 + 1, 0), WW - 1);
        int y0c = min(max(y0, 0), HH - 1), y1c = min(max(y0 + 1, 0), HH - 1);
        sOff[wv][e] = make_int4((y0c * WW + x0c) * CC, (y0c * WW + x1c) * CC,
                                (y1c * WW + x0c) * CC, (y1c * WW + x1c) * CC);
        sW[wv][e] = make_float4(w00, w01, w10, w11);
    }
    __syncthreads();

    const bf16* xb = xproj + (size_t)n * HW * CC + 2 * lane;
    int gbase = (lane >> 3) * 9;
    float a0 = 0.f, a1 = 0.f;
    #pragma unroll
    for (int p = 0; p < 9; ++p) {
        int4 o = sOff[wv][gbase + p];
        float4 w = sW[wv][gbase + p];
        bf162 v00 = *(const bf162*)(xb + o.x);
        bf162 v01 = *(const bf162*)(xb + o.y);
        bf162 v10 = *(const bf162*)(xb + o.z);
        bf162 v11 = *(const bf162*)(xb + o.w);
        a0 += w.x * b2f(v00.x) + w.y * b2f(v01.x) + w.z * b2f(v10.x) + w.w * b2f(v11.x);
        a1 += w.x * b2f(v00.y) + w.y * b2f(v01.y) + w.z * b2f(v10.y) + w.w * b2f(v11.y);
    }
    bf162 o2; o2.x = f2b(a0); o2.y = f2b(a1);
    ((bf162*)out)[(size_t)pix * 64 + lane] = o2;
}

// ---------------- MFMA GEMM, K=128-specialized: single-stage, ONE barrier.
// R3: both call sites have K=128. The generic K-loop cost 4 barriers (2 staging
// phases x 2). Full 64x128 A+B tiles staged at once (34.8KB LDS -> 4 blocks/CU),
// all 8 staging loads in flight together, then 4 uninterrupted MFMA k-steps.
__global__ __launch_bounds__(256) void gemm_mfma_kernel(
    const bf16* __restrict__ A, const bf16* __restrict__ Wt,
    const float* __restrict__ bias, bf16* __restrict__ Out, int M, int Nn)
{
    __shared__ __align__(16) __bf16 As[64][136];
    __shared__ __align__(16) __bf16 Bs[64][136];
    int tid = threadIdx.x;
    int wv = tid >> 6, lane = tid & 63;
    int bm = blockIdx.y * 64, bn = blockIdx.x * 64;
    int mI = lane & 15, q = lane >> 4;

    // stage full tiles: s = 0..1023 -> row = s>>4, ko = (s&15)*8
    #pragma unroll
    for (int i = 0; i < 4; ++i) {
        int s = tid + 256 * i;
        int row = s >> 4, ko = (s & 15) * 8;
        *reinterpret_cast<uint4*>(&As[row][ko]) =
            *reinterpret_cast<const uint4*>(A + (size_t)(bm + row) * 128 + ko);
        int ng = bn + row;
        uint4 bv = make_uint4(0, 0, 0, 0);
        if (ng < Nn) bv = *reinterpret_cast<const uint4*>(Wt + (size_t)ng * 128 + ko);
        *reinterpret_cast<uint4*>(&Bs[row][ko]) = bv;
    }
    __syncthreads();

    floatx4 acc[4] = {};
    #pragma unroll
    for (int ks = 0; ks < 4; ++ks) {
        int k = ks * 32 + q * 8;
        bf16x8 a = *reinterpret_cast<const bf16x8*>(&As[wv * 16 + mI][k]);
        #pragma unroll
        for (int t = 0; t < 4; ++t) {
            bf16x8 b = *reinterpret_cast<const bf16x8*>(&Bs[t * 16 + mI][k]);
            acc[t] = MFMA(a, b, acc[t]);
        }
    }
    int row0 = bm + wv * 16 + q * 4;
    #pragma unroll
    for (int t = 0; t < 4; ++t) {
        int col = bn + t * 16 + mI;
        if (col >= Nn) continue;
        float bs = bias[col];
        #pragma unroll
        for (int r = 0; r < 4; ++r)
            st1(Out + (size_t)(row0 + r) * Nn + col, acc[t][r] + bs);
    }
}

// ---------------- fused tail, v2 (proven 49.4us) restored verbatim.
// R1-R3 ledger: 32-row=57us, wave-private=107us, register-xres=70us (spilled:
// +90MB scratch traffic at VGPR 84). v2's structure is the local optimum;
// keep it byte-for-byte.
__global__ __launch_bounds__(256, 3) void fused_tail_kernel(
    const bf16* __restrict__ ycore, const float* __restrict__ x,
    const bf16* __restrict__ w_outT, const float* __restrict__ b_out,
    const float* __restrict__ ln2g, const float* __restrict__ ln2b,
    const bf16* __restrict__ w1T, const float* __restrict__ b1,
    const bf16* __restrict__ w2T, const float* __restrict__ b2,
    float* __restrict__ out)
{
    __shared__ __align__(16) bf16 sA[64 * 136];      // ycore stage, then h1 quarter
    __shared__ __align__(16) bf16 sXres[64 * 136];
    __shared__ __align__(16) bf16 sH2[64 * 136];
    int tid = threadIdx.x, wv = tid >> 6, lane = tid & 63;
    int mI = lane & 15, q = lane >> 4;
    int bm = blockIdx.x * 64;

    // prefetch GEMM0 B-frags (8 independent 16B loads, in flight during staging)
    bf16x8 bw0[4][2];
    #pragma unroll
    for (int ks = 0; ks < 4; ++ks)
        #pragma unroll
        for (int ct = 0; ct < 2; ++ct)
            bw0[ks][ct] = *reinterpret_cast<const bf16x8*>(
                w_outT + (size_t)(wv * 32 + ct * 16 + mI) * 128 + ks * 32 + q * 8);

    // stage ycore tile (64 x 128) at stride 136
    #pragma unroll
    for (int i = 0; i < 4; ++i) {
        int s = tid + 256 * i;
        int row = s >> 4, ko = (s & 15) * 8;
        *reinterpret_cast<uint4*>(&sA[row * 136 + ko]) =
            *reinterpret_cast<const uint4*>(ycore + (size_t)(bm + row) * 128 + ko);
    }
    __syncthreads();

    // GEMM0: wave covers out-proj cols wv*32..+31
    floatx4 acc0[4][2] = {};
    #pragma unroll
    for (int ks = 0; ks < 4; ++ks) {
        int k = ks * 32 + q * 8;
        bf16x8 a[4];
        #pragma unroll
        for (int rt = 0; rt < 4; ++rt)
            a[rt] = *reinterpret_cast<const bf16x8*>(&sA[(rt * 16 + mI) * 136 + k]);
        #pragma unroll
        for (int ct = 0; ct < 2; ++ct)
            #pragma unroll
            for (int rt = 0; rt < 4; ++rt)
                acc0[rt][ct] = MFMA(a[rt], bw0[ks][ct], acc0[rt][ct]);
    }
    // xres tile -> sXres (bf16), with x residual (f32 global)
    #pragma unroll
    for (int rt = 0; rt < 4; ++rt)
        #pragma unroll
        for (int ct = 0; ct < 2; ++ct) {
            int col = wv * 32 + ct * 16 + mI;
            float bs = b_out[col];
            #pragma unroll
            for (int r = 0; r < 4; ++r) {
                int row = rt * 16 + q * 4 + r;
                float v = acc0[rt][ct][r] + bs + x[(size_t)(bm + row) * 128 + col];
                sXres[row * 136 + col] = f2b(v);
            }
        }
    __syncthreads();

    // LN2: thread -> (row = tid>>2, 32 channels), quad shuffle reduce
    {
        int row = tid >> 2, part = tid & 3;
        float s = 0.f, sq = 0.f;
        float vals[32];
        #pragma unroll
        for (int j = 0; j < 4; ++j) {
            bf16x8 v = *reinterpret_cast<const bf16x8*>(&sXres[row * 136 + part * 32 + j * 8]);
            #pragma unroll
            for (int e = 0; e < 8; ++e) {
                float f = (float)v[e];
                vals[j * 8 + e] = f; s += f; sq += f * f;
            }
        }
        s  += __shfl_xor(s, 1);  s += __shfl_xor(s, 2);
        sq += __shfl_xor(sq, 1); sq += __shfl_xor(sq, 2);
        float mean = s * (1.0f / 128.0f);
        float rstd = rsqrtf(sq * (1.0f / 128.0f) - mean * mean + 1e-5f);
        #pragma unroll
        for (int j = 0; j < 4; ++j) {
            bf16x8 o;
            #pragma unroll
            for (int e = 0; e < 8; ++e) {
                int ch = part * 32 + j * 8 + e;
                bf16 t = f2b((vals[j * 8 + e] - mean) * rstd * ln2g[ch] + ln2b[ch]);
                o[e] = *reinterpret_cast<__bf16*>(&t);
            }
            *reinterpret_cast<bf16x8*>(&sH2[row * 136 + part * 32 + j * 8]) = o;
        }
    }
    __syncthreads();

    // MLP in four 128-col quarter-phases over the hidden dim
    floatx4 acc2[4][2] = {};
    #pragma unroll 1
    for (int ph = 0; ph < 4; ++ph) {
        // hoist GEMM1 B-frags (hidden cols ph*128 + wv*32..+31): 8 loads in flight
        bf16x8 bw1[4][2];
        #pragma unroll
        for (int ks = 0; ks < 4; ++ks)
            #pragma unroll
            for (int ct = 0; ct < 2; ++ct)
                bw1[ks][ct] = *reinterpret_cast<const bf16x8*>(
                    w1T + (size_t)(ph * 128 + wv * 32 + ct * 16 + mI) * 128 + ks * 32 + q * 8);
        // GEMM1: h1 quarter cols wv*32..+31
        floatx4 acc1[4][2] = {};
        #pragma unroll
        for (int ks = 0; ks < 4; ++ks) {
            int k = ks * 32 + q * 8;
            bf16x8 a[4];
            #pragma unroll
            for (int rt = 0; rt < 4; ++rt)
                a[rt] = *reinterpret_cast<const bf16x8*>(&sH2[(rt * 16 + mI) * 136 + k]);
            #pragma unroll
            for (int ct = 0; ct < 2; ++ct)
                #pragma unroll
                for (int rt = 0; rt < 4; ++rt)
                    acc1[rt][ct] = MFMA(a[rt], bw1[ks][ct], acc1[rt][ct]);
        }
        __syncthreads();   // all waves done reading sA from previous phase
        // hoist GEMM2 B-frags now; they fly during the gelu VALU burst
        bf16x8 bw2[4][2];
        #pragma unroll
        for (int ks = 0; ks < 4; ++ks)
            #pragma unroll
            for (int ct = 0; ct < 2; ++ct)
                bw2[ks][ct] = *reinterpret_cast<const bf16x8*>(
                    w2T + (size_t)(wv * 32 + ct * 16 + mI) * 512 + ph * 128 + ks * 32 + q * 8);
        // gelu -> sA (h1 quarter, local cols wv*32..+31)
        #pragma unroll
        for (int rt = 0; rt < 4; ++rt)
            #pragma unroll
            for (int ct = 0; ct < 2; ++ct) {
                int lcol = wv * 32 + ct * 16 + mI;
                float bs = b1[ph * 128 + lcol];
                #pragma unroll
                for (int r = 0; r < 4; ++r) {
                    int row = rt * 16 + q * 4 + r;
                    sA[row * 136 + lcol] = f2b(gelu_exact(acc1[rt][ct][r] + bs));
                }
            }
        __syncthreads();
        // GEMM2 partial-K: out cols wv*32..+31, K-local = 128
        #pragma unroll
        for (int ks = 0; ks < 4; ++ks) {
            int k = ks * 32 + q * 8;
            bf16x8 a[4];
            #pragma unroll
            for (int rt = 0; rt < 4; ++rt)
                a[rt] = *reinterpret_cast<const bf16x8*>(&sA[(rt * 16 + mI) * 136 + k]);
            #pragma unroll
            for (int ct = 0; ct < 2; ++ct)
                #pragma unroll
                for (int rt = 0; rt < 4; ++rt)
                    acc2[rt][ct] = MFMA(a[rt], bw2[ks][ct], acc2[rt][ct]);
        }
    }
    // epilogue: out = acc2 + b2 + xres  (f32)
    #pragma unroll
    for (int rt = 0; rt < 4; ++rt)
        #pragma unroll
        for (int ct = 0; ct < 2; ++ct) {
            int col = wv * 32 + ct * 16 + mI;
            float bs = b2[col];
            #pragma unroll
            for (int r = 0; r < 4; ++r) {
                int row = rt * 16 + q * 4 + r;
                out[(size_t)(bm + row) * 128 + col] =
                    acc2[rt][ct][r] + bs + b2f(sXres[row * 136 + col]);
            }
        }
}

extern "C" void kernel_launch(void* const* d_in, const int* in_sizes, int n_in,
                              void* d_out, int out_size, void* d_ws, size_t ws_size,
                              hipStream_t stream)
{
    const float* x     = (const float*)d_in[0];
    const float* ln1g  = (const float*)d_in[1];
    const float* ln1b  = (const float*)d_in[2];
    const float* w_in  = (const float*)d_in[3];
    const float* b_in  = (const float*)d_in[4];
    const float* dw_k  = (const float*)d_in[5];
    const float* dw_b  = (const float*)d_in[6];
    const float* dwg   = (const float*)d_in[7];
    const float* dwb   = (const float*)d_in[8];
    const float* w_off = (const float*)d_in[9];
    const float* b_off = (const float*)d_in[10];
    const float* w_msk = (const float*)d_in[11];
    const float* b_msk = (const float*)d_in[12];
    const float* w_out = (const float*)d_in[13];
    const float* b_out = (const float*)d_in[14];
    const float* ln2g  = (const float*)d_in[15];
    const float* ln2b  = (const float*)d_in[16];
    const float* w1    = (const float*)d_in[17];
    const float* b1    = (const float*)d_in[18];
    const float* w2    = (const float*)d_in[19];
    const float* b2    = (const float*)d_in[20];
    float* out = (float*)d_out;

    // activations (bf16): xln(128)->ycore | xproj(128) | x1(128) | omr(216)
    bf16* ws = (bf16*)d_ws;
    bf16* xln   = ws;
    bf16* xproj = xln   + (size_t)NPIX * 128;
    bf16* x1    = xproj + (size_t)NPIX * 128;
    bf16* omr   = x1    + (size_t)NPIX * 128;
    bf16* ycore = xln;                  // xln dead after dwconv
    // bf16 transposed weights after activations (600/pix)
    bf16* wT    = ws + (size_t)NPIX * 600;
    bf16* w_inT  = wT;                  // 128x128
    bf16* w_omT  = w_inT  + 16384;      // 216x128 (off 144 + msk 72)
    bf16* w_outT = w_omT  + 27648;      // 128x128
    bf16* w1T    = w_outT + 16384;      // 512x128
    bf16* w2T    = w1T    + 65536;      // 128x512
    float* b_om  = (float*)(w2T + 65536);  // 216 f32
    const int WTOT = 191488 + 216;

    PrepArgs pa;
    pa.src[0] = w_in;  pa.dst[0] = w_inT;            pa.K[0] = 128; pa.N[0] = 128;
    pa.src[1] = w_off; pa.dst[1] = w_omT;            pa.K[1] = 128; pa.N[1] = 144;
    pa.src[2] = w_msk; pa.dst[2] = w_omT + 144*128;  pa.K[2] = 128; pa.N[2] = 72;
    pa.src[3] = w_out; pa.dst[3] = w_outT;           pa.K[3] = 128; pa.N[3] = 128;
    pa.src[4] = w1;    pa.dst[4] = w1T;              pa.K[4] = 128; pa.N[4] = 512;
    pa.src[5] = w2;    pa.dst[5] = w2T;              pa.K[5] = 512; pa.N[5] = 128;
    pa.cum[0] = 0;     pa.cum[1] = 16384;  pa.cum[2] = 34816; pa.cum[3] = 44032;
    pa.cum[4] = 60416; pa.cum[5] = 125952; pa.cum[6] = 191488;
    pa.b_off = b_off;  pa.b_msk = b_msk;   pa.b_om = b_om;

    const int M = NPIX;          // 36864
    dim3 blk(256);

    // 0. weight prep (+ bias concat)
    prep_weights<<<(WTOT + 255) / 256, blk, 0, stream>>>(pa, WTOT);
    // 1. xln = LN1(x)
    ln_kernel<float, bf16><<<NPIX / 4, blk, 0, stream>>>(x, ln1g, ln1b, xln);
    // 2. xproj = xln @ w_in + b_in   (K=128 single-stage gemm)
    gemm_mfma_kernel<<<dim3(2, M / 64), blk, 0, stream>>>(
        xln, w_inT, b_in, xproj, M, 128);
    // 3. x1 = gelu(LN(dwconv(xln) + dw_b))
    dwconv_ln_gelu_kernel<<<NPIX / 4, blk, 0, stream>>>(xln, dw_k, dw_b, dwg, dwb, x1);
    // 4. omr = x1 @ [w_off | w_msk] + [b_off | b_msk]   (N=216 fused)
    gemm_mfma_kernel<<<dim3(4, M / 64), blk, 0, stream>>>(
        x1, w_omT, b_om, omr, M, 216);
    // 5. ycore = dcnv3(xproj, omr)  [softmax fused in]
    dcn_core_kernel<<<NPIX / 4, blk, 0, stream>>>(xproj, omr, ycore);
    // 6-9. fused: outproj + residual + LN2 + MLP + residual  (v2 restored)
    fused_tail_kernel<<<M / 64, blk, 0, stream>>>(
        ycore, x, w_outT, b_out, ln2g, ln2b, w1T, b1, w2T, b2, out);
}